// Round 5
// baseline (670.362 us; speedup 1.0000x reference)
//
#include <hip/hip_runtime.h>
#include <hip/hip_bf16.h>

// Problem constants (fixed by the reference)
#define NN   100000      // nodes
#define NE   1600000     // edges
#define MPAD 100096      // 782 * 128  (padded rows for 128-row GEMM tiles)
#define BK   64          // bucket slots per node (in-deg ~Poisson(16); P(>=64)~2e-13)
// Output: h_t (NN*128) then c_t (NN*128), fp32.

typedef __attribute__((ext_vector_type(8))) short bf16x8;
typedef __attribute__((ext_vector_type(4))) float f32x4;
typedef __attribute__((ext_vector_type(8))) unsigned short u16x8;

// ---- workspace layout (bytes) ----
#define OFF_DEG  0ull           // NN f32 (pad 400,384); zeroed with cursor
#define OFF_CUR  400384ull      // NN i32
#define OFF_XH   800768ull      // MPAD*256 bf16 interleaved x|h (51,249,152)
#define OFF_FP   52049920ull    // MPAD*256 bf16 [Lx|Lh]      (51,249,152)
#define OFF_WT   103299072ull   // 512*512 bf16 (524,288)
#define OFF_BIAS 103823360ull   // 512 f32 (pad 2048)
#define OFF_GP   103825408ull   // 512*MPAD bf16 COL-MAJOR partial gates (102,498,304)
#define WS_NEED  206323712ull   // ws bytes needed for the split-gemm path
// Buckets (NN*64 uint2 = 51.2 MB) live in d_out (dead before gemm overwrites out).

__device__ __forceinline__ unsigned short f2bf(float f) {
    unsigned int u = __float_as_uint(f);
    u += 0x7fffu + ((u >> 16) & 1u);
    return (unsigned short)(u >> 16);
}
__device__ __forceinline__ float bf2f(unsigned short u) {
    return __uint_as_float(((unsigned int)u) << 16);
}
__device__ __forceinline__ float sigf(float x)  { return 1.f / (1.f + __expf(-x)); }
__device__ __forceinline__ float tanhf_(float x){ return 1.f - 2.f / (__expf(2.f * x) + 1.f); }

typedef __attribute__((address_space(3))) void lds_void;
typedef __attribute__((address_space(1))) void g_void;
__device__ __forceinline__ void gload16(const void* g, void* l) {
    __builtin_amdgcn_global_load_lds((const g_void*)g, (lds_void*)l, 16, 0, 0);
}

// ---- K1: zero deg+cursor  ||  pack W (B^T, gate-interleaved) + bias ----
__global__ void zero_packw_kernel(float4* __restrict__ z,
                                  const float* __restrict__ Wx0, const float* __restrict__ Wx1,
                                  const float* __restrict__ Wh0, const float* __restrict__ Wh1,
                                  const float* __restrict__ bx,  const float* __restrict__ bh,
                                  unsigned short* __restrict__ Wt, float* __restrict__ bias) {
    int b = blockIdx.x;
    if (b < 196) {
        int t = b * 256 + threadIdx.x;
        if (t < 50048) z[t] = make_float4(0.f, 0.f, 0.f, 0.f);
        return;
    }
    int t = (b - 196) * 256 + threadIdx.x;   // 0 .. 512*512-1
    int col = t >> 9, k = t & 511;
    int h = col >> 2, g = col & 3;
    const float* W; int kk;
    if      (k < 128) { W = Wx0; kk = k; }
    else if (k < 256) { W = Wx1; kk = k - 128; }
    else if (k < 384) { W = Wh0; kk = k - 256; }
    else              { W = Wh1; kk = k - 384; }
    float v = W[((size_t)(g << 7) + kk) * 128 + h];
    Wt[(size_t)col * 512 + k] = f2bf(v);
    if (k == 0) bias[col] = bx[(g << 7) + h] + bh[(g << 7) + h];
}

// ---- K2: edge atomics+bucket  ⊥  GEMM1 (gates partial over [x|h])  ||  cvt ----
// Atomic stream is rate-bound with all pipes idle (r4: VALUBusy 3%, MfmaUtil 0,
// HBM 11%); gemm1 (graph-independent half of the gates GEMM, K=256) and cvt
// run in that shadow. gemm1 reads x/h fp32 directly (no XH race), writes bf16
// partial to Gp (col-major). Edge/gemm1 blocks interleaved mod 3 for
// immediate co-residency; cvt blocks backfill.
#define MIX_BLOCKS 9408     // 3*3136: r=b%3 (0->gemm1 g=b/3; 1,2->edge chunks)
#define CVT_BLOCKS 25024    // MPAD*64/256
__global__ void mega2_kernel(const int* __restrict__ src, const int* __restrict__ dst,
                             const float* __restrict__ ew,
                             float* __restrict__ deg, int* __restrict__ cursor,
                             uint2* __restrict__ bkt,
                             const float* __restrict__ x, const float* __restrict__ hp,
                             unsigned short* __restrict__ XH,
                             const unsigned short* __restrict__ Wtu,
                             unsigned short* __restrict__ Gp,
                             int with_g1) {
    __shared__ __align__(16) short s1a[2][4096];   // gemm1 A dbuf (128x32 bf16)
    __shared__ __align__(16) short s1b[2][4096];   // gemm1 B dbuf

    const int b = blockIdx.x;
    int eid = -1, g1 = -1, cvt = -1;
    if (with_g1) {
        if (b < MIX_BLOCKS) {
            int r = b % 3, g = b / 3;
            if (r == 0) g1 = g;
            else if (g < 3125) eid = (r - 1) * 3125 + g;
            else return;
        } else cvt = b - MIX_BLOCKS;
    } else {
        if (b < 6250) eid = b;
        else cvt = b - 6250;
    }

    if (eid >= 0) {                               // ---- edge block ----
        int e = eid * 256 + threadIdx.x;          // NE = 6250*256 exactly
        int s = src[e], d = dst[e];
        float w = ew[e];
        atomicAdd(&deg[s], w);
        int pos = atomicAdd(&cursor[d], 1);
        if (pos < BK) {                           // overflow guard (P ~ 2e-13)
            uint2 v; v.x = (unsigned)s; v.y = __float_as_uint(w);
            bkt[((size_t)d << 6) + pos] = v;
        }
        return;
    }
    if (cvt >= 0) {                               // ---- cvt block ----
        int t = cvt * 256 + threadIdx.x;          // 0 .. MPAD*64-1
        int n = t >> 6, q = t & 63;
        ushort4 o = make_ushort4(0, 0, 0, 0);
        if (n < NN) {
            const float* s = (q < 32) ? (x + (size_t)n * 128 + (q << 2))
                                      : (hp + (size_t)n * 128 + ((q - 32) << 2));
            float4 v = *(const float4*)s;
            o = make_ushort4(f2bf(v.x), f2bf(v.y), f2bf(v.z), f2bf(v.w));
        }
        *(ushort4*)(XH + (size_t)n * 256 + (q << 2)) = o;
        return;
    }

    // ---- gemm1 block: acc += [x|h](fp32->bf16) . Wt[k in 0-127,256-383] ----
    const int ntile = (g1 >> 3) & 3;
    const int mtile = (g1 & 7) | ((g1 >> 5) << 3);
    if (mtile >= 782) return;
    const size_t m0 = (size_t)mtile * 128;
    const int n0 = ntile * 128;

    const int tid  = threadIdx.x;
    const int lane = tid & 63;
    const int wave = tid >> 6;
    const int wm = wave >> 1, wn = wave & 1;
    const int lr = lane & 15, lq = lane >> 4;

    const short* Wt = (const short*)Wtu;
    const int ar  = tid >> 2;                     // staged row 0..63 (+64)
    const int ac  = tid & 3;                      // 8-elem chunk
    const int sxw = ((ac ^ ((ar >> 1) & 3)) << 3);   // T2 swizzled chunk (shorts)
    const short* gB = Wt + (size_t)(n0 + ar) * 512 + sxw;

    const int xr = (lr >> 1) & 3;
    int offA[4], offB[4];
#pragma unroll
    for (int i = 0; i < 4; ++i) {
        offA[i] = (wm * 64 + i * 16 + lr) * 32 + ((lq ^ xr) << 3);
        offB[i] = (wn * 64 + i * 16 + lr) * 32 + ((lq ^ xr) << 3);
    }

    f32x4 acc[4][4];
#pragma unroll
    for (int i = 0; i < 4; ++i)
#pragma unroll
        for (int j = 0; j < 4; ++j) acc[i][j] = (f32x4){0.f, 0.f, 0.f, 0.f};

    auto ldsA = [&](int s, int buf) {             // fp32 load -> bf16 -> swizzled LDS
#pragma unroll
        for (int half = 0; half < 2; ++half) {
            int row = ar + half * 64;
            size_t grow = m0 + row;
            float v[8];
            if (grow < NN) {
                const float* p = (s < 4 ? x + grow * 128 + s * 32
                                        : hp + grow * 128 + (s - 4) * 32) + ac * 8;
                float4 a0 = *(const float4*)p;
                float4 a1 = *(const float4*)(p + 4);
                v[0] = a0.x; v[1] = a0.y; v[2] = a0.z; v[3] = a0.w;
                v[4] = a1.x; v[5] = a1.y; v[6] = a1.z; v[7] = a1.w;
            } else {
#pragma unroll
                for (int q = 0; q < 8; ++q) v[q] = 0.f;
            }
            u16x8 o;
#pragma unroll
            for (int q = 0; q < 8; ++q) o[q] = f2bf(v[q]);
            *(u16x8*)&s1a[buf][row * 32 + sxw] = o;
        }
    };
    auto stB = [&](int s, int buf) {              // Wt k: 0-127 (x) / 256-383 (h)
        int ktw = (s < 4) ? s : s + 4;
        gload16(gB + ktw * 32,            &s1b[buf][wave * 512]);
        gload16(gB + ktw * 32 + 64 * 512, &s1b[buf][2048 + wave * 512]);
    };

    stB(0, 0); ldsA(0, 0);
    __syncthreads();
    for (int s = 0; s < 8; ++s) {                 // simple dbuf; hidden by atomics
        const int buf = s & 1;
        if (s < 7) { stB(s + 1, buf ^ 1); ldsA(s + 1, buf ^ 1); }
        bf16x8 af[4], bfr[4];
#pragma unroll
        for (int i = 0; i < 4; ++i) af[i]  = *(const bf16x8*)&s1a[buf][offA[i]];
#pragma unroll
        for (int i = 0; i < 4; ++i) bfr[i] = *(const bf16x8*)&s1b[buf][offB[i]];
#pragma unroll
        for (int i = 0; i < 4; ++i)
#pragma unroll
            for (int j = 0; j < 4; ++j)
                acc[i][j] = __builtin_amdgcn_mfma_f32_16x16x32_bf16(af[i], bfr[j], acc[i][j], 0, 0, 0);
        __syncthreads();
    }

    // Gp col-major store: lane's 4 row-values are consecutive -> one 8B store.
#pragma unroll
    for (int i = 0; i < 4; ++i)
#pragma unroll
        for (int j = 0; j < 4; ++j) {
            int col = n0 + wn * 64 + j * 16 + lr;
            size_t rowb = m0 + wm * 64 + i * 16 + lq * 4;
            ushort4 o = make_ushort4(f2bf(acc[i][j][0]), f2bf(acc[i][j][1]),
                                     f2bf(acc[i][j][2]), f2bf(acc[i][j][3]));
            *(ushort4*)(Gp + (size_t)col * MPAD + rowb) = o;
        }
}

// One wave per node; 4 edge slots (16 lanes x 32B each) run concurrently so
// 4 row-gathers are in flight; bucket entry for the NEXT step is software-
// pipelined over the current row gather. Norm inline from deg (L2-hot).
__launch_bounds__(256)
__global__ void gather_pack_kernel(const float* __restrict__ deg,
                                   const int* __restrict__ cursor,
                                   const uint2* __restrict__ bkt,
                                   const unsigned short* __restrict__ XH,
                                   unsigned short* __restrict__ Fp) {
    int node = (blockIdx.x * 256 + threadIdx.x) >> 6;
    int lane = threadIdx.x & 63;
    if (node >= MPAD) return;
    const int g  = lane >> 4;
    const int li = lane & 15;
    unsigned short* Frow = Fp + (size_t)node * 256;
    if (node >= NN) {
        if (g < 2) *(uint4*)(Frow + li * 16 + g * 8) = make_uint4(0, 0, 0, 0);
        return;
    }
    int cnt = cursor[node];
    cnt = cnt > BK ? BK : cnt;
    float dd = deg[node];
    float disd = dd > 0.f ? rsqrtf(dd) : 0.f;
    const uint2* row = bkt + ((size_t)node << 6);
    float acc[16];
#pragma unroll
    for (int k = 0; k < 16; ++k) acc[k] = 0.f;

    int e = g;
    uint2 ce;
    if (e < cnt) ce = row[e];
    while (e < cnt) {
        uint2 cur = ce;
        int en = e + 4;
        if (en < cnt) ce = row[en];
        float dsv = deg[cur.x];
        const unsigned short* xr = XH + (size_t)cur.x * 256 + li * 16;
        u16x8 v0 = *(const u16x8*)(xr);
        u16x8 v1 = *(const u16x8*)(xr + 8);
        float diss = dsv > 0.f ? rsqrtf(dsv) : 0.f;
        float nm = -(diss * __uint_as_float(cur.y) * disd);
#pragma unroll
        for (int k = 0; k < 8; ++k) acc[k]     += nm * bf2f((unsigned short)v0[k]);
#pragma unroll
        for (int k = 0; k < 8; ++k) acc[k + 8] += nm * bf2f((unsigned short)v1[k]);
        e = en;
    }
#pragma unroll
    for (int k = 0; k < 16; ++k) {
        acc[k] += __shfl_xor(acc[k], 16, 64);
        acc[k] += __shfl_xor(acc[k], 32, 64);
    }
    if (g < 2) {
        u16x8 o;
#pragma unroll
        for (int k = 0; k < 8; ++k)
            o[k] = f2bf((g & 1) ? acc[k + 8] : acc[k]);
        *(u16x8*)(Frow + li * 16 + g * 8) = o;
    }
}

__device__ __forceinline__ f32x4 shflx4(f32x4 v, int m) {
    f32x4 r;
    r[0] = __shfl_xor(v[0], m, 64);
    r[1] = __shfl_xor(v[1], m, 64);
    r[2] = __shfl_xor(v[2], m, 64);
    r[3] = __shfl_xor(v[3], m, 64);
    return r;
}
__device__ __forceinline__ float sel4(f32x4 v, int k) {
    float r = v[0];
    r = (k == 1) ? v[1] : r;
    r = (k == 2) ? v[2] : r;
    r = (k == 3) ? v[3] : r;
    return r;
}
__device__ __forceinline__ float pick4(float a0, float a1, float a2, float a3, int k) {
    float r = a0;
    r = (k == 1) ? a1 : r;
    r = (k == 2) ? a2 : r;
    r = (k == 3) ? a3 : r;
    return r;
}

#define WAITV(n)  asm volatile("s_waitcnt vmcnt(" #n ")" ::: "memory")
#define WAITLGKM0 asm volatile("s_waitcnt lgkmcnt(0)" ::: "memory")

// K4: GEMM + LSTM epilogue. SPLIT=1: 8 K-steps over Fp only, acc init from Gp
// (bf16 partial of the [x|h] half computed in K2). SPLIT=0: full 16 K-steps
// (round-4 verified fallback when ws is too small for Gp). 4-deep LDS pipeline,
// counted vmcnt + raw s_barrier (T3+T4), T2 XOR-swizzle both sides, end-of-body
// lgkmcnt(0) pins read completion (race-free buffer rotation).
template <int SPLIT>
__launch_bounds__(256)
__global__ void gemm_lstm_kernel(const unsigned short* __restrict__ XHu,
                                 const unsigned short* __restrict__ Fpu,
                                 const unsigned short* __restrict__ Wtu,
                                 const float* __restrict__ bias,
                                 const float* __restrict__ c_prev,
                                 const unsigned short* __restrict__ Gp,
                                 float* __restrict__ out) {
    __shared__ __align__(16) short sa[4 * 4096];
    __shared__ __align__(16) short sb[4 * 4096];

    const int tid  = threadIdx.x;
    const int lane = tid & 63;
    const int wave = tid >> 6;
    const int wm = wave >> 1, wn = wave & 1;
    const int lr = lane & 15, lq = lane >> 4;

    const int b = blockIdx.x;                 // 0..3135
    const int ntile = (b >> 3) & 3;
    const int mtile = (b & 7) | ((b >> 5) << 3);
    if (mtile >= 782) return;
    const size_t m0 = (size_t)mtile * 128;
    const int n0 = ntile * 128;

    const short* XH = (const short*)XHu;
    const short* Fp = (const short*)Fpu;
    const short* Wt = (const short*)Wtu;

    const int arow = tid >> 2;
    const int sx   = (((tid & 3) ^ ((arow >> 1) & 3)) << 3);
    const size_t rowA = (m0 + arow) * 256 + sx;
    const short* gB = Wt + (size_t)(n0 + arow) * 512 + sx;

    const int rbase = wm * 64 + lq * 4 + (lr & 3);
    const int hbase = (n0 >> 2) + wn * 16 + (lr >> 2);

    const int xr = (lr >> 1) & 3;
    int offA[4], offB[4];
#pragma unroll
    for (int i = 0; i < 4; ++i) {
        offA[i] = (wm * 64 + i * 16 + lr) * 32 + ((lq ^ xr) << 3);
        offB[i] = (wn * 64 + i * 16 + lr) * 32 + ((lq ^ xr) << 3);
    }

    auto stage = [&](int kt, int b4) {
        const int buf = b4 << 12;
        const int off = ((kt >> 3) << 7) + ((kt & 3) << 5);
        const short* Ab = ((kt >> 2) & 1) ? Fp : XH;
        gload16(Ab + rowA + off,            &sa[buf + wave * 512]);
        gload16(Ab + rowA + 64 * 256 + off, &sa[buf + 2048 + wave * 512]);
        gload16(gB + kt * 32,               &sb[buf + wave * 512]);
        gload16(gB + kt * 32 + 64 * 512,    &sb[buf + 2048 + wave * 512]);
    };
    auto ktOf = [&](int s) { return SPLIT ? (s < 4 ? s + 4 : s + 8) : s; };
    const int NS = SPLIT ? 8 : 16;

    f32x4 acc[4][4];
    if (SPLIT) {
        // issue Gp loads, then stages, then consume (no drain of stage loads)
        ushort4 gpt[4][4];
#pragma unroll
        for (int i = 0; i < 4; ++i)
#pragma unroll
            for (int j = 0; j < 4; ++j)
                gpt[i][j] = *(const ushort4*)(Gp +
                    (size_t)(n0 + wn * 64 + j * 16 + lr) * MPAD +
                    (m0 + wm * 64 + i * 16 + lq * 4));
        stage(ktOf(0), 0); stage(ktOf(1), 1); stage(ktOf(2), 2);
#pragma unroll
        for (int i = 0; i < 4; ++i)
#pragma unroll
            for (int j = 0; j < 4; ++j)
                acc[i][j] = (f32x4){bf2f(gpt[i][j].x), bf2f(gpt[i][j].y),
                                    bf2f(gpt[i][j].z), bf2f(gpt[i][j].w)};
    } else {
#pragma unroll
        for (int i = 0; i < 4; ++i)
#pragma unroll
            for (int j = 0; j < 4; ++j) acc[i][j] = (f32x4){0.f, 0.f, 0.f, 0.f};
        stage(0, 0); stage(1, 1); stage(2, 2);
    }

#pragma unroll
    for (int s = 0; s < NS; ++s) {
        if      (s <= NS - 3) WAITV(8);
        else if (s == NS - 2) WAITV(4);
        else                  WAITV(0);
        __builtin_amdgcn_sched_barrier(0);
        __builtin_amdgcn_s_barrier();
        if (s + 3 < NS) stage(ktOf(s + 3), (s + 3) & 3);
        const int buf = (s & 3) << 12;
        bf16x8 af[4], bfr[4];
#pragma unroll
        for (int i = 0; i < 4; ++i) af[i]  = *(const bf16x8*)&sa[buf + offA[i]];
#pragma unroll
        for (int i = 0; i < 4; ++i) bfr[i] = *(const bf16x8*)&sb[buf + offB[i]];
        __builtin_amdgcn_s_setprio(1);
#pragma unroll
        for (int i = 0; i < 4; ++i)
#pragma unroll
            for (int j = 0; j < 4; ++j)
                acc[i][j] = __builtin_amdgcn_mfma_f32_16x16x32_bf16(af[i], bfr[j], acc[i][j], 0, 0, 0);
        __builtin_amdgcn_s_setprio(0);
        WAITLGKM0;
        __builtin_amdgcn_sched_barrier(0);
    }

    float bs[4];
#pragma unroll
    for (int j = 0; j < 4; ++j) bs[j] = bias[n0 + wn * 64 + j * 16 + lr];
    float cp[4][4];
#pragma unroll
    for (int i = 0; i < 4; ++i) {
        size_t grow = m0 + rbase + i * 16;
#pragma unroll
        for (int j = 0; j < 4; ++j)
            cp[i][j] = (grow < NN) ? c_prev[grow * 128 + hbase + j * 4] : 0.f;
    }

    const int k = lr & 3;
#pragma unroll
    for (int i = 0; i < 4; ++i) {
        size_t grow = m0 + rbase + i * 16;
        if (grow >= NN) continue;
#pragma unroll
        for (int j = 0; j < 4; ++j) {
            f32x4 v0 = acc[i][j];
            v0[0] += bs[j]; v0[1] += bs[j]; v0[2] += bs[j]; v0[3] += bs[j];
            f32x4 v1 = shflx4(v0, 1);
            f32x4 v2 = shflx4(v0, 2);
            f32x4 v3 = shflx4(v0, 3);
            float vv0 = sel4(v0, k), vv1 = sel4(v1, k),
                  vv2 = sel4(v2, k), vv3 = sel4(v3, k);
            float gi = pick4(vv0, vv1, vv2, vv3, k);
            float gf = pick4(vv0, vv1, vv2, vv3, k ^ 1);
            float gg = pick4(vv0, vv1, vv2, vv3, k ^ 2);
            float go = pick4(vv0, vv1, vv2, vv3, k ^ 3);
            float iv = sigf(gi), fv = sigf(gf), gv = tanhf_(gg), ov = sigf(go);
            float ct = fv * cp[i][j] + iv * gv;
            float ht = ov * tanhf_(ct);
            int h = hbase + j * 4;
            out[grow * 128 + h] = ht;
            out[(size_t)NN * 128 + grow * 128 + h] = ct;
        }
    }
}

extern "C" void kernel_launch(void* const* d_in, const int* in_sizes, int n_in,
                              void* d_out, int out_size, void* d_ws, size_t ws_size,
                              hipStream_t stream) {
    const float* x      = (const float*)d_in[0];
    const int*   ei     = (const int*)  d_in[1];
    const float* ew     = (const float*)d_in[2];
    const float* h_prev = (const float*)d_in[3];
    const float* c_prev = (const float*)d_in[4];
    const float* Wx0    = (const float*)d_in[5];
    const float* Wx1    = (const float*)d_in[6];
    const float* Wh0    = (const float*)d_in[7];
    const float* Wh1    = (const float*)d_in[8];
    const float* bx     = (const float*)d_in[9];
    const float* bh     = (const float*)d_in[10];
    float* out = (float*)d_out;

    char* ws = (char*)d_ws;
    float*          deg    = (float*)(ws + OFF_DEG);
    int*            cursor = (int*)  (ws + OFF_CUR);
    unsigned short* XH     = (unsigned short*)(ws + OFF_XH);
    unsigned short* Fp     = (unsigned short*)(ws + OFF_FP);
    unsigned short* Wt     = (unsigned short*)(ws + OFF_WT);
    float*          bias   = (float*)(ws + OFF_BIAS);
    unsigned short* Gp     = (unsigned short*)(ws + OFF_GP);
    uint2*          bkt    = (uint2*)d_out;      // scratch; dead before K4 writes out

    const int* src = ei;
    const int* dst = ei + NE;

    const bool big = (ws_size >= WS_NEED);

    zero_packw_kernel<<<196 + 1024, 256, 0, stream>>>(
        (float4*)ws, Wx0, Wx1, Wh0, Wh1, bx, bh, Wt, bias);

    if (big) {
        mega2_kernel<<<MIX_BLOCKS + CVT_BLOCKS, 256, 0, stream>>>(
            src, dst, ew, deg, cursor, bkt, x, h_prev, XH, Wt, Gp, 1);
        gather_pack_kernel<<<MPAD / 4, 256, 0, stream>>>(deg, cursor, bkt, XH, Fp);
        gemm_lstm_kernel<1><<<3136, 256, 0, stream>>>(XH, Fp, Wt, bias, c_prev, Gp, out);
    } else {
        mega2_kernel<<<6250 + CVT_BLOCKS, 256, 0, stream>>>(
            src, dst, ew, deg, cursor, bkt, x, h_prev, XH, Wt, Gp, 0);
        gather_pack_kernel<<<MPAD / 4, 256, 0, stream>>>(deg, cursor, bkt, XH, Fp);
        gemm_lstm_kernel<0><<<3136, 256, 0, stream>>>(XH, Fp, Wt, bias, c_prev, Gp, out);
    }
}

// Round 6
// 627.970 us; speedup vs baseline: 1.0675x; 1.0675x over previous
//
#include <hip/hip_runtime.h>
#include <hip/hip_bf16.h>

// Problem constants (fixed by the reference)
#define NN   100000      // nodes
#define NE   1600000     // edges
#define MPAD 100096      // 782 * 128  (padded rows for 128-row GEMM tiles)
#define BK   64          // bucket slots per node (in-deg ~Poisson(16); P(>=64)~2e-13)
// Output: h_t (NN*128) then c_t (NN*128), fp32.

typedef __attribute__((ext_vector_type(8))) short bf16x8;
typedef __attribute__((ext_vector_type(4))) float f32x4;
typedef __attribute__((ext_vector_type(8))) unsigned short u16x8;

// ---- workspace layout (bytes) ----  (~103.8 MB total)
#define OFF_DEG  0ull           // NN f32 (pad 400,384); zeroed with cursor
#define OFF_CUR  400384ull      // NN i32
#define OFF_XH   800768ull      // MPAD*256 bf16 interleaved x|h (51,249,152)
#define OFF_FP   52049920ull    // MPAD*256 bf16 [Lx|Lh]      (51,249,152)
#define OFF_WT   103299072ull   // 512*512 bf16 (524,288)
#define OFF_BIAS 103823360ull   // 512 f32
// Buckets (NN*64 uint2 = 51.2 MB) live in d_out (dead before gemm overwrites out).

__device__ __forceinline__ unsigned short f2bf(float f) {
    unsigned int u = __float_as_uint(f);
    u += 0x7fffu + ((u >> 16) & 1u);
    return (unsigned short)(u >> 16);
}
__device__ __forceinline__ float bf2f(unsigned short u) {
    return __uint_as_float(((unsigned int)u) << 16);
}
__device__ __forceinline__ float sigf(float x)  { return 1.f / (1.f + __expf(-x)); }
__device__ __forceinline__ float tanhf_(float x){ return 1.f - 2.f / (__expf(2.f * x) + 1.f); }

typedef __attribute__((address_space(3))) void lds_void;
typedef __attribute__((address_space(1))) void g_void;
__device__ __forceinline__ void gload16(const void* g, void* l) {
    __builtin_amdgcn_global_load_lds((const g_void*)g, (lds_void*)l, 16, 0, 0);
}

// ---- K1: zero deg+cursor  ||  pack W (B^T, gate-interleaved) + bias ----
__global__ void zero_packw_kernel(float4* __restrict__ z,
                                  const float* __restrict__ Wx0, const float* __restrict__ Wx1,
                                  const float* __restrict__ Wh0, const float* __restrict__ Wh1,
                                  const float* __restrict__ bx,  const float* __restrict__ bh,
                                  unsigned short* __restrict__ Wt, float* __restrict__ bias) {
    int b = blockIdx.x;
    if (b < 196) {
        int t = b * 256 + threadIdx.x;
        if (t < 50048) z[t] = make_float4(0.f, 0.f, 0.f, 0.f);
        return;
    }
    int t = (b - 196) * 256 + threadIdx.x;   // 0 .. 512*512-1
    int col = t >> 9, k = t & 511;
    int h = col >> 2, g = col & 3;
    const float* W; int kk;
    if      (k < 128) { W = Wx0; kk = k; }
    else if (k < 256) { W = Wx1; kk = k - 128; }
    else if (k < 384) { W = Wh0; kk = k - 256; }
    else              { W = Wh1; kk = k - 384; }
    float v = W[((size_t)(g << 7) + kk) * 128 + h];
    Wt[(size_t)col * 512 + k] = f2bf(v);
    if (k == 0) bias[col] = bx[(g << 7) + h] + bh[(g << 7) + h];
}

// ---- K2: edge atomics+bucket (4 edges/thread, batched ILP)  ||  cvt ----
// deg_hist (fire-forget atomics) = 142us; r4 mega1 (1 dependent cursor->store
// chain per thread) = 218us. Batching 4 edges/thread issues 4 independent
// cursor atomics back-to-back -> one return-latency stall per 4 edges.
// cvt blocks backfill the idle BW behind the atomic stream.
#define EB 1563             // edge blocks, 1024 edges each (guarded tail)
#define CVT_BLOCKS 25024    // MPAD*64/256
__global__ void mega1_kernel(const int* __restrict__ src, const int* __restrict__ dst,
                             const float* __restrict__ ew,
                             float* __restrict__ deg, int* __restrict__ cursor,
                             uint2* __restrict__ bkt,
                             const float* __restrict__ x, const float* __restrict__ hp,
                             unsigned short* __restrict__ XH) {
    int b = blockIdx.x;
    if (b < EB) {                                 // ---- edge block ----
        int e0 = b * 1024 + threadIdx.x;
        int sarr[4], darr[4]; float warr[4]; bool ok[4];
#pragma unroll
        for (int k = 0; k < 4; ++k) {
            int e = e0 + k * 256;
            ok[k] = (e < NE);
            if (ok[k]) { sarr[k] = src[e]; darr[k] = dst[e]; warr[k] = ew[e]; }
        }
#pragma unroll
        for (int k = 0; k < 4; ++k)
            if (ok[k]) atomicAdd(&deg[sarr[k]], warr[k]);
        int pos[4];
#pragma unroll
        for (int k = 0; k < 4; ++k)
            if (ok[k]) pos[k] = atomicAdd(&cursor[darr[k]], 1);
#pragma unroll
        for (int k = 0; k < 4; ++k)
            if (ok[k] && pos[k] < BK) {           // overflow guard (P ~ 2e-13)
                uint2 v; v.x = (unsigned)sarr[k]; v.y = __float_as_uint(warr[k]);
                bkt[((size_t)darr[k] << 6) + pos[k]] = v;
            }
        return;
    }
    // ---- cvt block ----
    int t = (b - EB) * 256 + threadIdx.x;         // 0 .. MPAD*64-1
    int n = t >> 6, q = t & 63;
    ushort4 o = make_ushort4(0, 0, 0, 0);
    if (n < NN) {
        const float* s = (q < 32) ? (x + (size_t)n * 128 + (q << 2))
                                  : (hp + (size_t)n * 128 + ((q - 32) << 2));
        float4 v = *(const float4*)s;
        o = make_ushort4(f2bf(v.x), f2bf(v.y), f2bf(v.z), f2bf(v.w));
    }
    *(ushort4*)(XH + (size_t)n * 256 + (q << 2)) = o;
}

// One wave per node; 8 edge slots (8 lanes x 64B each) -> 8 row-gathers in
// flight, serial depth ceil(deg/8)~2. Bucket entry for the NEXT step is
// software-pipelined; 3-step shfl_xor(8,16,32) combines slots. Norm inline
// from deg (400KB, L2-hot).
__launch_bounds__(256)
__global__ void gather_pack_kernel(const float* __restrict__ deg,
                                   const int* __restrict__ cursor,
                                   const uint2* __restrict__ bkt,
                                   const unsigned short* __restrict__ XH,
                                   unsigned short* __restrict__ Fp) {
    int node = (blockIdx.x * 256 + threadIdx.x) >> 6;
    int lane = threadIdx.x & 63;
    if (node >= MPAD) return;
    const int g  = lane >> 3;                    // edge slot 0..7
    const int li = lane & 7;                     // col chunk: shorts [li*32, +32)
    unsigned short* Frow = Fp + (size_t)node * 256;
    if (node >= NN) {                            // pad rows -> zeros
        if (g < 4) *(uint4*)(Frow + li * 32 + g * 8) = make_uint4(0, 0, 0, 0);
        return;
    }
    int cnt = cursor[node];
    cnt = cnt > BK ? BK : cnt;                   // paired with fill-side guard
    float dd = deg[node];
    float disd = dd > 0.f ? rsqrtf(dd) : 0.f;
    const uint2* row = bkt + ((size_t)node << 6);
    float acc[32];
#pragma unroll
    for (int k = 0; k < 32; ++k) acc[k] = 0.f;

    int e = g;
    uint2 ce;
    if (e < cnt) ce = row[e];
    while (e < cnt) {
        uint2 cur = ce;
        int en = e + 8;
        if (en < cnt) ce = row[en];              // prefetch next entry
        float dsv = deg[cur.x];                  // random 4B, L2-hot
        const unsigned short* xr = XH + (size_t)cur.x * 256 + li * 32;
        u16x8 v0 = *(const u16x8*)(xr);
        u16x8 v1 = *(const u16x8*)(xr + 8);
        u16x8 v2 = *(const u16x8*)(xr + 16);
        u16x8 v3 = *(const u16x8*)(xr + 24);
        float diss = dsv > 0.f ? rsqrtf(dsv) : 0.f;
        float nm = -(diss * __uint_as_float(cur.y) * disd);
#pragma unroll
        for (int k = 0; k < 8; ++k) acc[k]      += nm * bf2f((unsigned short)v0[k]);
#pragma unroll
        for (int k = 0; k < 8; ++k) acc[k + 8]  += nm * bf2f((unsigned short)v1[k]);
#pragma unroll
        for (int k = 0; k < 8; ++k) acc[k + 16] += nm * bf2f((unsigned short)v2[k]);
#pragma unroll
        for (int k = 0; k < 8; ++k) acc[k + 24] += nm * bf2f((unsigned short)v3[k]);
        e = en;
    }
    // combine the 8 edge slots
#pragma unroll
    for (int k = 0; k < 32; ++k) {
        acc[k] += __shfl_xor(acc[k], 8, 64);
        acc[k] += __shfl_xor(acc[k], 16, 64);
        acc[k] += __shfl_xor(acc[k], 32, 64);
    }
    if (g < 4) {                                 // 32 lanes x 16B cover 512B row
        u16x8 o;
#pragma unroll
        for (int k = 0; k < 8; ++k)
            o[k] = f2bf(acc[g * 8 + k]);
        *(u16x8*)(Frow + li * 32 + g * 8) = o;
    }
}

__device__ __forceinline__ f32x4 shflx4(f32x4 v, int m) {
    f32x4 r;
    r[0] = __shfl_xor(v[0], m, 64);
    r[1] = __shfl_xor(v[1], m, 64);
    r[2] = __shfl_xor(v[2], m, 64);
    r[3] = __shfl_xor(v[3], m, 64);
    return r;
}
__device__ __forceinline__ float sel4(f32x4 v, int k) {
    float r = v[0];
    r = (k == 1) ? v[1] : r;
    r = (k == 2) ? v[2] : r;
    r = (k == 3) ? v[3] : r;
    return r;
}
__device__ __forceinline__ float pick4(float a0, float a1, float a2, float a3, int k) {
    float r = a0;
    r = (k == 1) ? a1 : r;
    r = (k == 2) ? a2 : r;
    r = (k == 3) ? a3 : r;
    return r;
}

#define WAITV(n)  asm volatile("s_waitcnt vmcnt(" #n ")" ::: "memory")
#define WAITLGKM0 asm volatile("s_waitcnt lgkmcnt(0)" ::: "memory")

// K4: GEMM 128x128 tile/block + LSTM epilogue (round-3/4 verified form).
// 4-deep LDS pipeline (A+B, 64KB), prefetch dist 3, counted vmcnt(8/4/0) +
// raw s_barrier (T3+T4); stage(kt+3) after the barrier; end-of-body
// lgkmcnt(0) pins read completion (race-free rotation). T2 XOR-swizzle on
// both sides. Register-only LSTM epilogue via shfl_xor gate exchange.
__launch_bounds__(256)
__global__ void gemm_lstm_kernel(const unsigned short* __restrict__ XHu,
                                 const unsigned short* __restrict__ Fpu,
                                 const unsigned short* __restrict__ Wtu,
                                 const float* __restrict__ bias,
                                 const float* __restrict__ c_prev,
                                 float* __restrict__ out) {
    __shared__ __align__(16) short sa[4 * 4096];   // 4 bufs x 128 rows x 32 shorts
    __shared__ __align__(16) short sb[4 * 4096];

    const int tid  = threadIdx.x;
    const int lane = tid & 63;
    const int wave = tid >> 6;
    const int wm = wave >> 1, wn = wave & 1;
    const int lr = lane & 15, lq = lane >> 4;

    // XCD co-schedule: blocks {k,k+8,k+16,k+24} share mtile -> same XCD L2.
    const int b = blockIdx.x;                 // 0..3135
    const int ntile = (b >> 3) & 3;
    const int mtile = (b & 7) | ((b >> 5) << 3);
    if (mtile >= 782) return;
    const size_t m0 = (size_t)mtile * 128;
    const int n0 = ntile * 128;

    const short* XH = (const short*)XHu;
    const short* Fp = (const short*)Fpu;
    const short* Wt = (const short*)Wtu;

    const int arow = tid >> 2;                    // 0..63
    const int sx   = (((tid & 3) ^ ((arow >> 1) & 3)) << 3);  // shorts
    const size_t rowA = (m0 + arow) * 256 + sx;   // XH/Fp share row stride 256
    const short* gB = Wt + (size_t)(n0 + arow) * 512 + sx;

    const int rbase = wm * 64 + lq * 4 + (lr & 3);   // local row this lane outputs
    const int hbase = (n0 >> 2) + wn * 16 + (lr >> 2);

    const int xr = (lr >> 1) & 3;                 // (row>>1)&3 for row=16a+lr
    int offA[4], offB[4];
#pragma unroll
    for (int i = 0; i < 4; ++i) {
        offA[i] = (wm * 64 + i * 16 + lr) * 32 + ((lq ^ xr) << 3);
        offB[i] = (wn * 64 + i * 16 + lr) * 32 + ((lq ^ xr) << 3);
    }

    f32x4 acc[4][4];
#pragma unroll
    for (int i = 0; i < 4; ++i)
#pragma unroll
        for (int j = 0; j < 4; ++j) acc[i][j] = (f32x4){0.f, 0.f, 0.f, 0.f};

    auto stage = [&](int kt) {
        const int buf = (kt & 3) << 12;           // buf base (shorts)
        const int off = ((kt >> 3) << 7) + ((kt & 3) << 5);  // col in XH/Fp row
        const short* Ab = ((kt >> 2) & 1) ? Fp : XH;
        gload16(Ab + rowA + off,            &sa[buf + wave * 512]);
        gload16(Ab + rowA + 64 * 256 + off, &sa[buf + 2048 + wave * 512]);
        gload16(gB + kt * 32,               &sb[buf + wave * 512]);
        gload16(gB + kt * 32 + 64 * 512,    &sb[buf + 2048 + wave * 512]);
    };

    stage(0); stage(1); stage(2);

#pragma unroll
    for (int kt = 0; kt < 16; ++kt) {
        if      (kt <= 13) WAITV(8);
        else if (kt == 14) WAITV(4);
        else               WAITV(0);
        __builtin_amdgcn_sched_barrier(0);
        __builtin_amdgcn_s_barrier();
        if (kt + 3 < 16) stage(kt + 3);
        const int buf = (kt & 3) << 12;
        bf16x8 af[4], bfr[4];
#pragma unroll
        for (int i = 0; i < 4; ++i) af[i]  = *(const bf16x8*)&sa[buf + offA[i]];
#pragma unroll
        for (int i = 0; i < 4; ++i) bfr[i] = *(const bf16x8*)&sb[buf + offB[i]];
        __builtin_amdgcn_s_setprio(1);
#pragma unroll
        for (int i = 0; i < 4; ++i)
#pragma unroll
            for (int j = 0; j < 4; ++j)
                acc[i][j] = __builtin_amdgcn_mfma_f32_16x16x32_bf16(af[i], bfr[j], acc[i][j], 0, 0, 0);
        __builtin_amdgcn_s_setprio(0);
        WAITLGKM0;                       // pin completion of this iter's ds_reads
        __builtin_amdgcn_sched_barrier(0);
    }

    float bs[4];
#pragma unroll
    for (int j = 0; j < 4; ++j) bs[j] = bias[n0 + wn * 64 + j * 16 + lr];
    float cp[4][4];
#pragma unroll
    for (int i = 0; i < 4; ++i) {
        size_t grow = m0 + rbase + i * 16;
#pragma unroll
        for (int j = 0; j < 4; ++j)
            cp[i][j] = (grow < NN) ? c_prev[grow * 128 + hbase + j * 4] : 0.f;
    }

    const int k = lr & 3;
#pragma unroll
    for (int i = 0; i < 4; ++i) {
        size_t grow = m0 + rbase + i * 16;
        if (grow >= NN) continue;
#pragma unroll
        for (int j = 0; j < 4; ++j) {
            f32x4 v0 = acc[i][j];
            v0[0] += bs[j]; v0[1] += bs[j]; v0[2] += bs[j]; v0[3] += bs[j];
            f32x4 v1 = shflx4(v0, 1);
            f32x4 v2 = shflx4(v0, 2);
            f32x4 v3 = shflx4(v0, 3);
            float vv0 = sel4(v0, k), vv1 = sel4(v1, k),
                  vv2 = sel4(v2, k), vv3 = sel4(v3, k);
            float gi = pick4(vv0, vv1, vv2, vv3, k);       // gate 0 (i)
            float gf = pick4(vv0, vv1, vv2, vv3, k ^ 1);   // gate 1 (f)
            float gg = pick4(vv0, vv1, vv2, vv3, k ^ 2);   // gate 2 (g)
            float go = pick4(vv0, vv1, vv2, vv3, k ^ 3);   // gate 3 (o)
            float iv = sigf(gi), fv = sigf(gf), gv = tanhf_(gg), ov = sigf(go);
            float ct = fv * cp[i][j] + iv * gv;
            float ht = ov * tanhf_(ct);
            int h = hbase + j * 4;
            out[grow * 128 + h] = ht;
            out[(size_t)NN * 128 + grow * 128 + h] = ct;
        }
    }
}

extern "C" void kernel_launch(void* const* d_in, const int* in_sizes, int n_in,
                              void* d_out, int out_size, void* d_ws, size_t ws_size,
                              hipStream_t stream) {
    const float* x      = (const float*)d_in[0];
    const int*   ei     = (const int*)  d_in[1];
    const float* ew     = (const float*)d_in[2];
    const float* h_prev = (const float*)d_in[3];
    const float* c_prev = (const float*)d_in[4];
    const float* Wx0    = (const float*)d_in[5];
    const float* Wx1    = (const float*)d_in[6];
    const float* Wh0    = (const float*)d_in[7];
    const float* Wh1    = (const float*)d_in[8];
    const float* bx     = (const float*)d_in[9];
    const float* bh     = (const float*)d_in[10];
    float* out = (float*)d_out;

    char* ws = (char*)d_ws;
    float*          deg    = (float*)(ws + OFF_DEG);
    int*            cursor = (int*)  (ws + OFF_CUR);
    unsigned short* XH     = (unsigned short*)(ws + OFF_XH);
    unsigned short* Fp     = (unsigned short*)(ws + OFF_FP);
    unsigned short* Wt     = (unsigned short*)(ws + OFF_WT);
    float*          bias   = (float*)(ws + OFF_BIAS);
    uint2*          bkt    = (uint2*)d_out;      // 51.2MB scratch; dead before gemm

    const int* src = ei;
    const int* dst = ei + NE;

    zero_packw_kernel<<<196 + 1024, 256, 0, stream>>>(
        (float4*)ws, Wx0, Wx1, Wh0, Wh1, bx, bh, Wt, bias);

    mega1_kernel<<<EB + CVT_BLOCKS, 256, 0, stream>>>(
        src, dst, ew, deg, cursor, bkt, x, h_prev, XH);

    gather_pack_kernel<<<MPAD / 4, 256, 0, stream>>>(deg, cursor, bkt, XH, Fp);

    gemm_lstm_kernel<<<3136, 256, 0, stream>>>(XH, Fp, Wt, bias, c_prev, out);
}